// Round 1
// baseline (925.744 us; speedup 1.0000x reference)
//
#include <hip/hip_runtime.h>
#include <math.h>

// Problem constants (fixed by reference): B=4, S=2048, D=512, H=8, R=8, dk=64
#define B_ 4
#define S_ 2048
#define D_ 512
#define H_ 8
#define R_ 8
#define DK_ 64
#define NEDGE (B_*H_*2*R_*S_)   // 1,048,576 edges

#define TILE 64
#define KT 16

// C[m,n] = sum_k A[m,k] * W[n,k] + bias[n]
// a_bhsd: A is [B,H,S,dk] with m=b*S+s, k=h*64+d
// c_bhsd: C is [B,H,S,dk] with m=b*S+s, n=h*64+d
__global__ __launch_bounds__(256) void gemm_xwt(
    const float* __restrict__ A, const float* __restrict__ W,
    const float* __restrict__ bias, float* __restrict__ C,
    int M, int N, int K, int a_bhsd, int c_bhsd)
{
    __shared__ float As[KT][TILE + 4];
    __shared__ float Ws[KT][TILE + 4];
    const int m0 = blockIdx.x * TILE;
    const int n0 = blockIdx.y * TILE;
    const int t  = threadIdx.x;
    const int tx = t & 15, ty = t >> 4;
    float acc[4][4] = {};

    for (int kk = 0; kk < K; kk += KT) {
        // stage A tile and W tile (64 rows x 16 k) into LDS, [k][row] layout
        for (int idx = t; idx < TILE * KT; idx += 256) {
            int row = idx >> 4, col = idx & 15;
            int m = m0 + row, k = kk + col;
            float aval;
            if (a_bhsd) {
                int b = m >> 11, s = m & (S_ - 1);
                int h = k >> 6,  d = k & 63;
                aval = A[((((size_t)b * H_ + h) * S_ + s) << 6) + d];
            } else {
                aval = A[(size_t)m * K + k];
            }
            As[col][row] = aval;
            int n = n0 + row;
            Ws[col][row] = W[(size_t)n * K + k];
        }
        __syncthreads();
        #pragma unroll
        for (int k = 0; k < KT; ++k) {
            float4 av = *(const float4*)&As[k][ty << 2];
            float4 bv = *(const float4*)&Ws[k][tx << 2];
            acc[0][0] += av.x * bv.x; acc[0][1] += av.x * bv.y; acc[0][2] += av.x * bv.z; acc[0][3] += av.x * bv.w;
            acc[1][0] += av.y * bv.x; acc[1][1] += av.y * bv.y; acc[1][2] += av.y * bv.z; acc[1][3] += av.y * bv.w;
            acc[2][0] += av.z * bv.x; acc[2][1] += av.z * bv.y; acc[2][2] += av.z * bv.z; acc[2][3] += av.z * bv.w;
            acc[3][0] += av.w * bv.x; acc[3][1] += av.w * bv.y; acc[3][2] += av.w * bv.z; acc[3][3] += av.w * bv.w;
        }
        __syncthreads();
    }

    #pragma unroll
    for (int i = 0; i < 4; ++i) {
        int m = m0 + (ty << 2) + i;
        #pragma unroll
        for (int j = 0; j < 4; ++j) {
            int n = n0 + (tx << 2) + j;
            float v = acc[i][j] + bias[n];
            if (c_bhsd) {
                int b = m >> 11, s = m & (S_ - 1);
                int h = n >> 6,  d = n & 63;
                C[((((size_t)b * H_ + h) * S_ + s) << 6) + d] = v;
            } else {
                C[(size_t)m * N + n] = v;
            }
        }
    }
}

// One wave (64 lanes) per edge. e = ((b*H + h)*2R + r2)*S + s
__global__ __launch_bounds__(256) void edge_scores(
    const float* __restrict__ q, const float* __restrict__ k_,
    const int* __restrict__ start_nodes, const int* __restrict__ end_nodes,
    const float* __restrict__ rel_q, const float* __restrict__ rel_k,
    float* __restrict__ sflat, float* __restrict__ denom)
{
    int e    = blockIdx.x * 4 + (threadIdx.x >> 6);
    int lane = threadIdx.x & 63;
    if (e >= NEDGE) return;

    int s   = e & (S_ - 1);
    int tmp = e >> 11;
    int r2  = tmp & 15; tmp >>= 4;
    int h   = tmp & 7;
    int b   = tmp >> 3;
    int r   = r2 & 7;

    int idx_base = ((b * H_ + h) * R_ + r) * S_ + s;
    int sn_raw = start_nodes[idx_base];
    int en     = end_nodes[idx_base];
    bool masked = (sn_raw == -1) || (r2 == 0);
    int sn = (sn_raw == -1) ? 0 : sn_raw;
    int qi = (r2 < R_) ? en : sn;
    int ki = (r2 < R_) ? sn : en;

    size_t head_off = ((size_t)b * H_ + h) * S_;
    float qv = q [((head_off + qi) << 6) + lane];
    float kv = k_[((head_off + ki) << 6) + lane];
    float rq = rel_q[((h * 16 + r2) << 6) + lane];
    float rk = rel_k[((h * 16 + r2) << 6) + lane];

    float p = qv * kv + qv * rk + rq * kv;
    #pragma unroll
    for (int off = 32; off >= 1; off >>= 1)
        p += __shfl_xor(p, off);

    if (lane == 0) {
        float sf = masked ? 0.0f : expf(p * (1.0f / 24.0f));  // 3*sqrt(64)=24
        sflat[e] = sf;
        if (sf != 0.0f)
            atomicAdd(&denom[(b * H_ + h) * S_ + qi], sf);
    }
}

__global__ __launch_bounds__(256) void edge_scatter(
    const float* __restrict__ v_, const int* __restrict__ start_nodes,
    const int* __restrict__ end_nodes, const float* __restrict__ rel_v,
    const float* __restrict__ sflat, const float* __restrict__ denom,
    float* __restrict__ attn)
{
    int e    = blockIdx.x * 4 + (threadIdx.x >> 6);
    int lane = threadIdx.x & 63;
    if (e >= NEDGE) return;

    float sf = sflat[e];
    if (sf == 0.0f) return;   // masked or underflowed: contributes exactly 0

    int s   = e & (S_ - 1);
    int tmp = e >> 11;
    int r2  = tmp & 15; tmp >>= 4;
    int h   = tmp & 7;
    int b   = tmp >> 3;
    int r   = r2 & 7;

    int idx_base = ((b * H_ + h) * R_ + r) * S_ + s;
    int sn_raw = start_nodes[idx_base];
    int en     = end_nodes[idx_base];
    int sn = (sn_raw == -1) ? 0 : sn_raw;
    int qi = (r2 < R_) ? en : sn;
    int ki = (r2 < R_) ? sn : en;

    size_t head_off = ((size_t)b * H_ + h) * S_;
    float den  = denom[(b * H_ + h) * S_ + qi];   // > 0 since sf > 0 contributed
    float prob = sf / den;
    float vv = v_[((head_off + ki) << 6) + lane] + rel_v[((h * 16 + r2) << 6) + lane];
    atomicAdd(&attn[((head_off + qi) << 6) + lane], prob * vv);
}

extern "C" void kernel_launch(void* const* d_in, const int* in_sizes, int n_in,
                              void* d_out, int out_size, void* d_ws, size_t ws_size,
                              hipStream_t stream) {
    const float* query = (const float*)d_in[0];
    const float* key   = (const float*)d_in[1];
    const float* value = (const float*)d_in[2];
    const int* start_nodes = (const int*)d_in[3];
    const int* end_nodes   = (const int*)d_in[4];
    const float* rel_q = (const float*)d_in[5];
    const float* rel_k = (const float*)d_in[6];
    const float* rel_v = (const float*)d_in[7];
    const float* Wq = (const float*)d_in[8];
    const float* bq = (const float*)d_in[9];
    const float* Wk = (const float*)d_in[10];
    const float* bk = (const float*)d_in[11];
    const float* Wv = (const float*)d_in[12];
    const float* bv = (const float*)d_in[13];
    const float* Wo = (const float*)d_in[14];
    const float* bo = (const float*)d_in[15];
    float* out = (float*)d_out;

    // Workspace layout (floats):
    //   q:     [0, 4M)        k: [4M, 8M)      v: [8M, 12M)
    //   attn:  [12M, 16M)     denom: [16M, 16M+65536)
    //   sflat: [16M+65536, 16M+65536+1M)
    const size_t NQ = (size_t)B_ * H_ * S_ * DK_;   // 4,194,304
    float* ws    = (float*)d_ws;
    float* q     = ws;
    float* k     = ws + NQ;
    float* v     = ws + 2 * NQ;
    float* attn  = ws + 3 * NQ;
    float* denom = ws + 4 * NQ;
    float* sflat = denom + (size_t)B_ * H_ * S_;

    // zero attn accumulator + denom (contiguous)
    hipMemsetAsync(attn, 0, (NQ + (size_t)B_ * H_ * S_) * sizeof(float), stream);

    const int M = B_ * S_;   // 8192
    dim3 ggrid(M / TILE, D_ / TILE);  // 128 x 8

    gemm_xwt<<<ggrid, 256, 0, stream>>>(query, Wq, bq, q, M, D_, D_, 0, 1);
    gemm_xwt<<<ggrid, 256, 0, stream>>>(key,   Wk, bk, k, M, D_, D_, 0, 1);
    gemm_xwt<<<ggrid, 256, 0, stream>>>(value, Wv, bv, v, M, D_, D_, 0, 1);

    const int nblk = NEDGE / 4;  // 4 waves per 256-thread block
    edge_scores <<<nblk, 256, 0, stream>>>(q, k, start_nodes, end_nodes, rel_q, rel_k, sflat, denom);
    edge_scatter<<<nblk, 256, 0, stream>>>(v, start_nodes, end_nodes, rel_v, sflat, denom, attn);

    gemm_xwt<<<ggrid, 256, 0, stream>>>(attn, Wo, bo, out, M, D_, D_, 1, 0);
}

// Round 2
// 673.359 us; speedup vs baseline: 1.3748x; 1.3748x over previous
//
#include <hip/hip_runtime.h>
#include <math.h>

// Problem constants (fixed by reference): B=4, S=2048, D=512, H=8, R=8, dk=64
#define B_ 4
#define S_ 2048
#define D_ 512
#define H_ 8
#define R_ 8
#define DK_ 64
#define NEDGE (B_*H_*2*R_*S_)   // 1,048,576 edges

typedef __attribute__((ext_vector_type(8))) short bf16x8;
typedef __attribute__((ext_vector_type(4))) float f32x4;

__device__ inline unsigned short f2bf(float f) {
    unsigned u = __builtin_bit_cast(unsigned, f);
    u += 0x7fffu + ((u >> 16) & 1u);   // RNE (no NaN inputs here)
    return (unsigned short)(u >> 16);
}

// ---------------- bf16-MFMA GEMM: C[m,n] = sum_k A[m,k]*W[n,k] + bias[n] ----
// Tile 64x64, BK=32, 4 waves (2x2), each wave 32x32 via 2x2 MFMA 16x16x32.
// a_bhsd: A is [B,H,S,dk] (m=b*S+s, k=h*64+d); c_bhsd: same for C output.
#define GTM 64
#define GTN 64
#define GBK 32
#define LSTRIDE 40   // 32 + 8 shorts pad (80 B rows, 16B-aligned)

__global__ __launch_bounds__(256) void gemm_mfma(
    const float* __restrict__ A, const float* __restrict__ W,
    const float* __restrict__ bias, float* __restrict__ C,
    int M, int N, int K, int a_bhsd, int c_bhsd)
{
    __shared__ unsigned short As[GTM * LSTRIDE];
    __shared__ unsigned short Bs[GTN * LSTRIDE];
    const int t    = threadIdx.x;
    const int lane = t & 63;
    const int wid  = t >> 6;
    const int wm   = wid >> 1, wn = wid & 1;
    const int m0   = blockIdx.x * GTM;
    const int n0   = blockIdx.y * GTN;

    f32x4 acc[2][2] = {};

    for (int kk = 0; kk < K; kk += GBK) {
        // stage: 64x32 A-tile + 64x32 W-tile, fp32 -> bf16 conversion in regs
        #pragma unroll
        for (int i = 0; i < 2; ++i) {
            int fidx = t + i * 256;          // 0..511
            int row = fidx >> 3;             // 0..63
            int kq  = fidx & 7;              // float4 slot within BK
            int k   = kk + kq * 4;

            const float* ap;
            if (a_bhsd) {
                int m = m0 + row;
                int b = m >> 11, s = m & (S_ - 1);
                int h = k >> 6,  d = k & 63;
                ap = &A[((((size_t)b * H_ + h) * S_ + s) << 6) + d];
            } else {
                ap = &A[(size_t)(m0 + row) * K + k];
            }
            float4 av = *(const float4*)ap;
            *(ushort4*)&As[row * LSTRIDE + kq * 4] =
                make_ushort4(f2bf(av.x), f2bf(av.y), f2bf(av.z), f2bf(av.w));

            float4 wv = *(const float4*)&W[(size_t)(n0 + row) * K + k];
            *(ushort4*)&Bs[row * LSTRIDE + kq * 4] =
                make_ushort4(f2bf(wv.x), f2bf(wv.y), f2bf(wv.z), f2bf(wv.w));
        }
        __syncthreads();

        // fragments: A[m=lane&15][k=(lane>>4)*8 + j], B mirrored (n=lane&15)
        bf16x8 af[2], bfr[2];
        #pragma unroll
        for (int mi = 0; mi < 2; ++mi)
            af[mi] = *(const bf16x8*)&As[(wm * 32 + mi * 16 + (lane & 15)) * LSTRIDE + (lane >> 4) * 8];
        #pragma unroll
        for (int nj = 0; nj < 2; ++nj)
            bfr[nj] = *(const bf16x8*)&Bs[(wn * 32 + nj * 16 + (lane & 15)) * LSTRIDE + (lane >> 4) * 8];
        #pragma unroll
        for (int mi = 0; mi < 2; ++mi)
            #pragma unroll
            for (int nj = 0; nj < 2; ++nj)
                acc[mi][nj] = __builtin_amdgcn_mfma_f32_16x16x32_bf16(af[mi], bfr[nj], acc[mi][nj], 0, 0, 0);
        __syncthreads();
    }

    // epilogue: C/D layout col = lane&15, row = (lane>>4)*4 + reg
    #pragma unroll
    for (int mi = 0; mi < 2; ++mi) {
        #pragma unroll
        for (int nj = 0; nj < 2; ++nj) {
            #pragma unroll
            for (int r = 0; r < 4; ++r) {
                int m = m0 + wm * 32 + mi * 16 + (lane >> 4) * 4 + r;
                int n = n0 + wn * 32 + nj * 16 + (lane & 15);
                float v = acc[mi][nj][r] + bias[n];
                if (c_bhsd) {
                    int b = m >> 11, s = m & (S_ - 1);
                    int h = n >> 6,  d = n & 63;
                    C[((((size_t)b * H_ + h) * S_ + s) << 6) + d] = v;
                } else {
                    C[(size_t)m * N + n] = v;
                }
            }
        }
    }
}

// ---------------- edge kernels (unchanged from R0) --------------------------
__global__ __launch_bounds__(256) void edge_scores(
    const float* __restrict__ q, const float* __restrict__ k_,
    const int* __restrict__ start_nodes, const int* __restrict__ end_nodes,
    const float* __restrict__ rel_q, const float* __restrict__ rel_k,
    float* __restrict__ sflat, float* __restrict__ denom)
{
    int e    = blockIdx.x * 4 + (threadIdx.x >> 6);
    int lane = threadIdx.x & 63;
    if (e >= NEDGE) return;

    int s   = e & (S_ - 1);
    int tmp = e >> 11;
    int r2  = tmp & 15; tmp >>= 4;
    int h   = tmp & 7;
    int b   = tmp >> 3;
    int r   = r2 & 7;

    int idx_base = ((b * H_ + h) * R_ + r) * S_ + s;
    int sn_raw = start_nodes[idx_base];
    int en     = end_nodes[idx_base];
    bool masked = (sn_raw == -1) || (r2 == 0);
    int sn = (sn_raw == -1) ? 0 : sn_raw;
    int qi = (r2 < R_) ? en : sn;
    int ki = (r2 < R_) ? sn : en;

    size_t head_off = ((size_t)b * H_ + h) * S_;
    float qv = q [((head_off + qi) << 6) + lane];
    float kv = k_[((head_off + ki) << 6) + lane];
    float rq = rel_q[((h * 16 + r2) << 6) + lane];
    float rk = rel_k[((h * 16 + r2) << 6) + lane];

    float p = qv * kv + qv * rk + rq * kv;
    #pragma unroll
    for (int off = 32; off >= 1; off >>= 1)
        p += __shfl_xor(p, off);

    if (lane == 0) {
        float sf = masked ? 0.0f : expf(p * (1.0f / 24.0f));  // 3*sqrt(64)=24
        sflat[e] = sf;
        if (sf != 0.0f)
            atomicAdd(&denom[(b * H_ + h) * S_ + qi], sf);
    }
}

__global__ __launch_bounds__(256) void edge_scatter(
    const float* __restrict__ v_, const int* __restrict__ start_nodes,
    const int* __restrict__ end_nodes, const float* __restrict__ rel_v,
    const float* __restrict__ sflat, const float* __restrict__ denom,
    float* __restrict__ attn)
{
    int e    = blockIdx.x * 4 + (threadIdx.x >> 6);
    int lane = threadIdx.x & 63;
    if (e >= NEDGE) return;

    float sf = sflat[e];
    if (sf == 0.0f) return;   // masked: contributes exactly 0

    int s   = e & (S_ - 1);
    int tmp = e >> 11;
    int r2  = tmp & 15; tmp >>= 4;
    int h   = tmp & 7;
    int b   = tmp >> 3;
    int r   = r2 & 7;

    int idx_base = ((b * H_ + h) * R_ + r) * S_ + s;
    int sn_raw = start_nodes[idx_base];
    int en     = end_nodes[idx_base];
    int sn = (sn_raw == -1) ? 0 : sn_raw;
    int qi = (r2 < R_) ? en : sn;
    int ki = (r2 < R_) ? sn : en;

    size_t head_off = ((size_t)b * H_ + h) * S_;
    float den  = denom[(b * H_ + h) * S_ + qi];
    float prob = sf / den;
    float vv = v_[((head_off + ki) << 6) + lane] + rel_v[((h * 16 + r2) << 6) + lane];
    atomicAdd(&attn[((head_off + qi) << 6) + lane], prob * vv);
}

extern "C" void kernel_launch(void* const* d_in, const int* in_sizes, int n_in,
                              void* d_out, int out_size, void* d_ws, size_t ws_size,
                              hipStream_t stream) {
    const float* query = (const float*)d_in[0];
    const float* key   = (const float*)d_in[1];
    const float* value = (const float*)d_in[2];
    const int* start_nodes = (const int*)d_in[3];
    const int* end_nodes   = (const int*)d_in[4];
    const float* rel_q = (const float*)d_in[5];
    const float* rel_k = (const float*)d_in[6];
    const float* rel_v = (const float*)d_in[7];
    const float* Wq = (const float*)d_in[8];
    const float* bq = (const float*)d_in[9];
    const float* Wk = (const float*)d_in[10];
    const float* bk = (const float*)d_in[11];
    const float* Wv = (const float*)d_in[12];
    const float* bv = (const float*)d_in[13];
    const float* Wo = (const float*)d_in[14];
    const float* bo = (const float*)d_in[15];
    float* out = (float*)d_out;

    const size_t NQ = (size_t)B_ * H_ * S_ * DK_;   // 4,194,304
    float* ws    = (float*)d_ws;
    float* q     = ws;
    float* k     = ws + NQ;
    float* v     = ws + 2 * NQ;
    float* attn  = ws + 3 * NQ;
    float* denom = ws + 4 * NQ;
    float* sflat = denom + (size_t)B_ * H_ * S_;

    hipMemsetAsync(attn, 0, (NQ + (size_t)B_ * H_ * S_) * sizeof(float), stream);

    const int M = B_ * S_;   // 8192
    dim3 ggrid(M / GTM, D_ / GTN);  // 128 x 8 = 1024 blocks

    gemm_mfma<<<ggrid, 256, 0, stream>>>(query, Wq, bq, q, M, D_, D_, 0, 1);
    gemm_mfma<<<ggrid, 256, 0, stream>>>(key,   Wk, bk, k, M, D_, D_, 0, 1);
    gemm_mfma<<<ggrid, 256, 0, stream>>>(value, Wv, bv, v, M, D_, D_, 0, 1);

    const int nblk = NEDGE / 4;
    edge_scores <<<nblk, 256, 0, stream>>>(q, k, start_nodes, end_nodes, rel_q, rel_k, sflat, denom);
    edge_scatter<<<nblk, 256, 0, stream>>>(v, start_nodes, end_nodes, rel_v, sflat, denom, attn);

    gemm_mfma<<<ggrid, 256, 0, stream>>>(attn, Wo, bo, out, M, D_, D_, 1, 0);
}

// Round 3
// 377.926 us; speedup vs baseline: 2.4495x; 1.7817x over previous
//
#include <hip/hip_runtime.h>
#include <math.h>

// Problem constants (fixed by reference): B=4, S=2048, D=512, H=8, R=8, dk=64
#define B_ 4
#define S_ 2048
#define D_ 512
#define H_ 8
#define R_ 8
#define DK_ 64
#define NEDGE (B_*H_*2*R_*S_)   // 1,048,576 edges
#define EPB   (2*R_*S_)         // 32768 edges per (b,h)

typedef __attribute__((ext_vector_type(8))) short bf16x8;
typedef __attribute__((ext_vector_type(4))) float f32x4;

__device__ inline unsigned short f2bf(float f) {
    unsigned u = __builtin_bit_cast(unsigned, f);
    u += 0x7fffu + ((u >> 16) & 1u);   // RNE (no NaN inputs here)
    return (unsigned short)(u >> 16);
}

// ---------------- bf16-MFMA GEMM: C[m,n] = sum_k A[m,k]*W[n,k] + bias[n] ----
#define GTM 64
#define GTN 64
#define GBK 32
#define LSTRIDE 40   // 32 + 8 shorts pad

__global__ __launch_bounds__(256) void gemm_mfma(
    const float* __restrict__ A, const float* __restrict__ W,
    const float* __restrict__ bias, float* __restrict__ C,
    int M, int N, int K, int a_bhsd, int c_bhsd)
{
    __shared__ unsigned short As[GTM * LSTRIDE];
    __shared__ unsigned short Bs[GTN * LSTRIDE];
    const int t    = threadIdx.x;
    const int lane = t & 63;
    const int wid  = t >> 6;
    const int wm   = wid >> 1, wn = wid & 1;
    const int m0   = blockIdx.x * GTM;
    const int n0   = blockIdx.y * GTN;

    f32x4 acc[2][2] = {};

    for (int kk = 0; kk < K; kk += GBK) {
        #pragma unroll
        for (int i = 0; i < 2; ++i) {
            int fidx = t + i * 256;
            int row = fidx >> 3;
            int kq  = fidx & 7;
            int k   = kk + kq * 4;

            const float* ap;
            if (a_bhsd) {
                int m = m0 + row;
                int b = m >> 11, s = m & (S_ - 1);
                int h = k >> 6,  d = k & 63;
                ap = &A[((((size_t)b * H_ + h) * S_ + s) << 6) + d];
            } else {
                ap = &A[(size_t)(m0 + row) * K + k];
            }
            float4 av = *(const float4*)ap;
            *(ushort4*)&As[row * LSTRIDE + kq * 4] =
                make_ushort4(f2bf(av.x), f2bf(av.y), f2bf(av.z), f2bf(av.w));

            float4 wv = *(const float4*)&W[(size_t)(n0 + row) * K + k];
            *(ushort4*)&Bs[row * LSTRIDE + kq * 4] =
                make_ushort4(f2bf(wv.x), f2bf(wv.y), f2bf(wv.z), f2bf(wv.w));
        }
        __syncthreads();

        bf16x8 af[2], bfr[2];
        #pragma unroll
        for (int mi = 0; mi < 2; ++mi)
            af[mi] = *(const bf16x8*)&As[(wm * 32 + mi * 16 + (lane & 15)) * LSTRIDE + (lane >> 4) * 8];
        #pragma unroll
        for (int nj = 0; nj < 2; ++nj)
            bfr[nj] = *(const bf16x8*)&Bs[(wn * 32 + nj * 16 + (lane & 15)) * LSTRIDE + (lane >> 4) * 8];
        #pragma unroll
        for (int mi = 0; mi < 2; ++mi)
            #pragma unroll
            for (int nj = 0; nj < 2; ++nj)
                acc[mi][nj] = __builtin_amdgcn_mfma_f32_16x16x32_bf16(af[mi], bfr[nj], acc[mi][nj], 0, 0, 0);
        __syncthreads();
    }

    #pragma unroll
    for (int mi = 0; mi < 2; ++mi) {
        #pragma unroll
        for (int nj = 0; nj < 2; ++nj) {
            #pragma unroll
            for (int r = 0; r < 4; ++r) {
                int m = m0 + wm * 32 + mi * 16 + (lane >> 4) * 4 + r;
                int n = n0 + wn * 32 + nj * 16 + (lane & 15);
                float v = acc[mi][nj][r] + bias[n];
                if (c_bhsd) {
                    int b = m >> 11, s = m & (S_ - 1);
                    int h = n >> 6,  d = n & 63;
                    C[((((size_t)b * H_ + h) * S_ + s) << 6) + d] = v;
                } else {
                    C[(size_t)m * N + n] = v;
                }
            }
        }
    }
}

// ---------------- CSR build: one block per (b,h), invert edges by dst -------
// Edge (r2,s): masked iff r2==0 || start==-1. dst = r2<R ? end : start,
// src(ki) = r2<R ? start : end. Packed entry: (r2<<11) | ki  (15 bits).
__global__ __launch_bounds__(1024) void build_csr(
    const int* __restrict__ start_nodes, const int* __restrict__ end_nodes,
    int* __restrict__ row_start, int* __restrict__ deg,
    unsigned short* __restrict__ csr)
{
    __shared__ int cnt[S_];      // 8 KB
    __shared__ int scan[1024];   // 4 KB
    const int bh = blockIdx.x;   // 0..31
    const int t  = threadIdx.x;
    const int base_idx = bh * (R_ * S_);

    for (int i = t; i < S_; i += 1024) cnt[i] = 0;
    __syncthreads();

    // Pass A: histogram destinations
    for (int f = t; f < EPB; f += 1024) {
        int r2 = f >> 11;
        int s  = f & (S_ - 1);
        if (r2 == 0) continue;
        int r  = r2 & 7;
        int sn = start_nodes[base_idx + r * S_ + s];
        if (sn == -1) continue;
        int en = end_nodes[base_idx + r * S_ + s];
        int dst = (r2 < R_) ? en : sn;
        atomicAdd(&cnt[dst], 1);
    }
    __syncthreads();

    // prefix-scan: each thread owns 2 bins
    int b0 = t * 2;
    int l0 = cnt[b0], l1 = cnt[b0 + 1];
    int tot = l0 + l1;
    scan[t] = tot;
    __syncthreads();
    for (int off = 1; off < 1024; off <<= 1) {
        int vv = (t >= off) ? scan[t - off] : 0;
        __syncthreads();
        scan[t] += vv;
        __syncthreads();
    }
    int ebase = scan[t] - tot;   // exclusive prefix
    int rs0 = ebase, rs1 = ebase + l0;
    row_start[bh * S_ + b0]     = rs0;  deg[bh * S_ + b0]     = l0;
    row_start[bh * S_ + b0 + 1] = rs1;  deg[bh * S_ + b0 + 1] = l1;
    __syncthreads();
    cnt[b0] = rs0; cnt[b0 + 1] = rs1;   // running placement offsets
    __syncthreads();

    // Pass B: place packed edges
    unsigned short* seg = csr + (size_t)bh * EPB;
    for (int f = t; f < EPB; f += 1024) {
        int r2 = f >> 11;
        int s  = f & (S_ - 1);
        if (r2 == 0) continue;
        int r  = r2 & 7;
        int sn = start_nodes[base_idx + r * S_ + s];
        if (sn == -1) continue;
        int en = end_nodes[base_idx + r * S_ + s];
        int dst = (r2 < R_) ? en : sn;
        int ki  = (r2 < R_) ? sn : en;
        int pos = atomicAdd(&cnt[dst], 1);
        seg[pos] = (unsigned short)((r2 << 11) | ki);
    }
}

// ---------------- fused score+softmax+aggregate, gather form ----------------
// One wave per (b,h,dst). Zero atomics; single 256B store per node.
__global__ __launch_bounds__(256) void edge_gather(
    const float* __restrict__ q, const float* __restrict__ k_,
    const float* __restrict__ v_,
    const float* __restrict__ rel_q, const float* __restrict__ rel_k,
    const float* __restrict__ rel_v,
    const int* __restrict__ row_start, const int* __restrict__ deg,
    const unsigned short* __restrict__ csr, float* __restrict__ attn)
{
    int g    = blockIdx.x * 4 + (threadIdx.x >> 6);   // 0..65535
    int lane = threadIdx.x & 63;
    int bh   = g >> 11;
    int dst  = g & (S_ - 1);
    int h    = bh & 7;
    size_t node_base = ((size_t)bh << 11);

    float qv = q[((node_base + dst) << 6) + lane];
    int rs = row_start[g];
    int n  = deg[g];
    const unsigned short* cs = csr + ((size_t)bh * EPB);

    float den = 0.f;
    float o   = 0.f;
    #pragma unroll 2
    for (int j = 0; j < n; ++j) {
        unsigned d = cs[rs + j];
        int ki = d & (S_ - 1);
        int r2 = d >> 11;
        float kv = k_[((node_base + ki) << 6) + lane];
        float rk = rel_k[(((h << 4) + r2) << 6) + lane];
        float rq = rel_q[(((h << 4) + r2) << 6) + lane];
        float p = qv * kv + qv * rk + rq * kv;
        #pragma unroll
        for (int off = 32; off >= 1; off >>= 1)
            p += __shfl_xor(p, off);
        float sf = __expf(p * (1.0f / 24.0f));   // 3*sqrt(64)=24
        float vv = v_[((node_base + ki) << 6) + lane];
        float rv = rel_v[(((h << 4) + r2) << 6) + lane];
        den += sf;
        o = fmaf(sf, vv + rv, o);
    }
    attn[((node_base + dst) << 6) + lane] = (den > 0.f) ? o / den : 0.f;
}

extern "C" void kernel_launch(void* const* d_in, const int* in_sizes, int n_in,
                              void* d_out, int out_size, void* d_ws, size_t ws_size,
                              hipStream_t stream) {
    const float* query = (const float*)d_in[0];
    const float* key   = (const float*)d_in[1];
    const float* value = (const float*)d_in[2];
    const int* start_nodes = (const int*)d_in[3];
    const int* end_nodes   = (const int*)d_in[4];
    const float* rel_q = (const float*)d_in[5];
    const float* rel_k = (const float*)d_in[6];
    const float* rel_v = (const float*)d_in[7];
    const float* Wq = (const float*)d_in[8];
    const float* bq = (const float*)d_in[9];
    const float* Wk = (const float*)d_in[10];
    const float* bk = (const float*)d_in[11];
    const float* Wv = (const float*)d_in[12];
    const float* bv = (const float*)d_in[13];
    const float* Wo = (const float*)d_in[14];
    const float* bo = (const float*)d_in[15];
    float* out = (float*)d_out;

    // Workspace layout (bytes):
    //   q, k, v, attn: 4 x 16 MB = 64 MB
    //   row_start, deg: 2 x 256 KB
    //   csr: 2 MB (uint16)
    const size_t NQ = (size_t)B_ * H_ * S_ * DK_;   // 4,194,304 floats
    float* ws    = (float*)d_ws;
    float* q     = ws;
    float* k     = ws + NQ;
    float* v     = ws + 2 * NQ;
    float* attn  = ws + 3 * NQ;
    int*   row_start = (int*)(ws + 4 * NQ);
    int*   deg       = row_start + (size_t)B_ * H_ * S_;
    unsigned short* csr = (unsigned short*)(deg + (size_t)B_ * H_ * S_);

    const int M = B_ * S_;   // 8192
    dim3 ggrid(M / GTM, D_ / GTN);  // 128 x 8

    build_csr<<<B_ * H_, 1024, 0, stream>>>(start_nodes, end_nodes, row_start, deg, csr);

    gemm_mfma<<<ggrid, 256, 0, stream>>>(query, Wq, bq, q, M, D_, D_, 0, 1);
    gemm_mfma<<<ggrid, 256, 0, stream>>>(key,   Wk, bk, k, M, D_, D_, 0, 1);
    gemm_mfma<<<ggrid, 256, 0, stream>>>(value, Wv, bv, v, M, D_, D_, 0, 1);

    edge_gather<<<(B_ * H_ * S_) / 4, 256, 0, stream>>>(
        q, k, v, rel_q, rel_k, rel_v, row_start, deg, csr, attn);

    gemm_mfma<<<ggrid, 256, 0, stream>>>(attn, Wo, bo, out, M, D_, D_, 1, 0);
}

// Round 4
// 344.485 us; speedup vs baseline: 2.6873x; 1.0971x over previous
//
#include <hip/hip_runtime.h>
#include <math.h>

// Problem constants (fixed by reference): B=4, S=2048, D=512, H=8, R=8, dk=64
#define B_ 4
#define S_ 2048
#define D_ 512
#define H_ 8
#define R_ 8
#define DK_ 64
#define EPB   (2*R_*S_)         // 32768 edges per (b,h)

typedef __attribute__((ext_vector_type(8))) short bf16x8;
typedef __attribute__((ext_vector_type(8))) unsigned short ushort8_t;
typedef __attribute__((ext_vector_type(4))) float f32x4;

__device__ inline unsigned short f2bf(float f) {
    unsigned u = __builtin_bit_cast(unsigned, f);
    u += 0x7fffu + ((u >> 16) & 1u);   // RNE (no NaN inputs here)
    return (unsigned short)(u >> 16);
}
__device__ inline float bf2f(unsigned short u) {
    return __builtin_bit_cast(float, ((unsigned)u) << 16);
}

// ---------------- fp32 -> bf16 converts -------------------------------------
__global__ __launch_bounds__(256) void cvt_big(
    const float* __restrict__ x0, const float* __restrict__ x1, const float* __restrict__ x2,
    unsigned short* __restrict__ y0, unsigned short* __restrict__ y1, unsigned short* __restrict__ y2)
{
    int z = blockIdx.y;
    const float* x = (z == 0) ? x0 : (z == 1) ? x1 : x2;
    unsigned short* y = (z == 0) ? y0 : (z == 1) ? y1 : y2;
    size_t i = ((size_t)blockIdx.x * 256 + threadIdx.x) * 4;
    float4 v = *(const float4*)&x[i];
    *(ushort4*)&y[i] = make_ushort4(f2bf(v.x), f2bf(v.y), f2bf(v.z), f2bf(v.w));
}

__global__ __launch_bounds__(256) void cvt_small(
    const float* __restrict__ x0, const float* __restrict__ x1,
    const float* __restrict__ x2, const float* __restrict__ x3,
    const float* __restrict__ x4, const float* __restrict__ x5, const float* __restrict__ x6,
    unsigned short* __restrict__ y0, unsigned short* __restrict__ y1,
    unsigned short* __restrict__ y2, unsigned short* __restrict__ y3,
    unsigned short* __restrict__ y4, unsigned short* __restrict__ y5, unsigned short* __restrict__ y6)
{
    int z = blockIdx.y;
    const float* xs[7] = {x0, x1, x2, x3, x4, x5, x6};
    unsigned short* ys[7] = {y0, y1, y2, y3, y4, y5, y6};
    int n = (z < 4) ? (D_ * D_) : (H_ * 2 * R_ * DK_);
    size_t i = ((size_t)blockIdx.x * 256 + threadIdx.x) * 4;
    if (i >= (size_t)n) return;
    float4 v = *(const float4*)&xs[z][i];
    *(ushort4*)&ys[z][i] = make_ushort4(f2bf(v.x), f2bf(v.y), f2bf(v.z), f2bf(v.w));
}

// ---------------- bf16 GEMM: C[m,n] = sum_k A[m,k]*W[n,k] + bias[n] ---------
// 128x128 tile, BK=64, 4 waves (2x2), each wave 64x64 via 4x4 MFMA 16x16x32.
// blockIdx.z selects among up to 3 (A,W,bias,C) problem instances (fused QKV).
// a_bhsd: A rows live in [B,H,S,dk] layout (k-block == one head, since BK=dk).
// If Cf != null, write fp32 row-major C (final GEMM); else bf16 [B,H,S,dk].
#define LSTR 72   // 64 + 8 shorts pad; 144 B rows, 16B-aligned, uniform banks

__global__ __launch_bounds__(256) void gemm_bf16(
    const unsigned short* __restrict__ A0, const unsigned short* __restrict__ A1,
    const unsigned short* __restrict__ A2,
    const unsigned short* __restrict__ W0, const unsigned short* __restrict__ W1,
    const unsigned short* __restrict__ W2,
    const float* __restrict__ bi0, const float* __restrict__ bi1, const float* __restrict__ bi2,
    unsigned short* __restrict__ C0, unsigned short* __restrict__ C1,
    unsigned short* __restrict__ C2,
    float* __restrict__ Cf, int a_bhsd)
{
    __shared__ unsigned short As[128 * LSTR];
    __shared__ unsigned short Bs[128 * LSTR];
    const int z = blockIdx.z;
    const unsigned short* A = (z == 0) ? A0 : (z == 1) ? A1 : A2;
    const unsigned short* W = (z == 0) ? W0 : (z == 1) ? W1 : W2;
    const float* bias        = (z == 0) ? bi0 : (z == 1) ? bi1 : bi2;
    unsigned short* C        = (z == 0) ? C0 : (z == 1) ? C1 : C2;

    const int t    = threadIdx.x;
    const int lane = t & 63;
    const int wid  = t >> 6;
    const int wm   = wid >> 1, wn = wid & 1;
    const int m0   = blockIdx.x * 128;
    const int n0   = blockIdx.y * 128;

    f32x4 acc[4][4] = {};

    for (int kk = 0; kk < D_; kk += 64) {
        // stage 128x64 A and 128x64 W (bf16), 16B chunks, coalesced
        #pragma unroll
        for (int i = 0; i < 4; ++i) {
            int fidx = t + i * 256;      // 0..1023
            int row  = fidx >> 3;        // 0..127
            int c    = fidx & 7;         // 16B chunk within 64-k row
            const unsigned short* ap;
            if (a_bhsd) {
                int m = m0 + row;
                int b = m >> 11, s = m & (S_ - 1);
                int h = kk >> 6;
                ap = A + ((((size_t)b * H_ + h) * S_ + s) << 6) + c * 8;
            } else {
                ap = A + (size_t)(m0 + row) * D_ + kk + c * 8;
            }
            *(ushort8_t*)&As[row * LSTR + c * 8] = *(const ushort8_t*)ap;
            *(ushort8_t*)&Bs[row * LSTR + c * 8] =
                *(const ushort8_t*)(W + (size_t)(n0 + row) * D_ + kk + c * 8);
        }
        __syncthreads();

        #pragma unroll
        for (int ks = 0; ks < 64; ks += 32) {
            bf16x8 af[4], bfr[4];
            #pragma unroll
            for (int mi = 0; mi < 4; ++mi)
                af[mi] = *(const bf16x8*)&As[(wm * 64 + mi * 16 + (lane & 15)) * LSTR + ks + (lane >> 4) * 8];
            #pragma unroll
            for (int nj = 0; nj < 4; ++nj)
                bfr[nj] = *(const bf16x8*)&Bs[(wn * 64 + nj * 16 + (lane & 15)) * LSTR + ks + (lane >> 4) * 8];
            #pragma unroll
            for (int mi = 0; mi < 4; ++mi)
                #pragma unroll
                for (int nj = 0; nj < 4; ++nj)
                    acc[mi][nj] = __builtin_amdgcn_mfma_f32_16x16x32_bf16(af[mi], bfr[nj], acc[mi][nj], 0, 0, 0);
        }
        __syncthreads();
    }

    // epilogue: C/D layout col = lane&15, row = (lane>>4)*4 + reg
    #pragma unroll
    for (int mi = 0; mi < 4; ++mi) {
        #pragma unroll
        for (int nj = 0; nj < 4; ++nj) {
            #pragma unroll
            for (int r = 0; r < 4; ++r) {
                int m = m0 + wm * 64 + mi * 16 + (lane >> 4) * 4 + r;
                int n = n0 + wn * 64 + nj * 16 + (lane & 15);
                float val = acc[mi][nj][r] + bias[n];
                if (Cf) {
                    Cf[(size_t)m * D_ + n] = val;
                } else {
                    int b = m >> 11, s = m & (S_ - 1);
                    int h = n >> 6,  d = n & 63;
                    C[((((size_t)b * H_ + h) * S_ + s) << 6) + d] = f2bf(val);
                }
            }
        }
    }
}

// ---------------- CSR build: one block per (b,h), invert edges by dst -------
__global__ __launch_bounds__(1024) void build_csr(
    const int* __restrict__ start_nodes, const int* __restrict__ end_nodes,
    int* __restrict__ row_start, int* __restrict__ deg,
    unsigned short* __restrict__ csr)
{
    __shared__ int cnt[S_];
    __shared__ int scan[1024];
    const int bh = blockIdx.x;
    const int t  = threadIdx.x;
    const int base_idx = bh * (R_ * S_);

    for (int i = t; i < S_; i += 1024) cnt[i] = 0;
    __syncthreads();

    for (int f = t; f < EPB; f += 1024) {
        int r2 = f >> 11;
        int s  = f & (S_ - 1);
        if (r2 == 0) continue;
        int r  = r2 & 7;
        int sn = start_nodes[base_idx + r * S_ + s];
        if (sn == -1) continue;
        int en = end_nodes[base_idx + r * S_ + s];
        int dst = (r2 < R_) ? en : sn;
        atomicAdd(&cnt[dst], 1);
    }
    __syncthreads();

    int b0 = t * 2;
    int l0 = cnt[b0], l1 = cnt[b0 + 1];
    int tot = l0 + l1;
    scan[t] = tot;
    __syncthreads();
    for (int off = 1; off < 1024; off <<= 1) {
        int vv = (t >= off) ? scan[t - off] : 0;
        __syncthreads();
        scan[t] += vv;
        __syncthreads();
    }
    int ebase = scan[t] - tot;
    int rs0 = ebase, rs1 = ebase + l0;
    row_start[bh * S_ + b0]     = rs0;  deg[bh * S_ + b0]     = l0;
    row_start[bh * S_ + b0 + 1] = rs1;  deg[bh * S_ + b0 + 1] = l1;
    __syncthreads();
    cnt[b0] = rs0; cnt[b0 + 1] = rs1;
    __syncthreads();

    unsigned short* seg = csr + (size_t)bh * EPB;
    for (int f = t; f < EPB; f += 1024) {
        int r2 = f >> 11;
        int s  = f & (S_ - 1);
        if (r2 == 0) continue;
        int r  = r2 & 7;
        int sn = start_nodes[base_idx + r * S_ + s];
        if (sn == -1) continue;
        int en = end_nodes[base_idx + r * S_ + s];
        int dst = (r2 < R_) ? en : sn;
        int ki  = (r2 < R_) ? sn : en;
        int pos = atomicAdd(&cnt[dst], 1);
        seg[pos] = (unsigned short)((r2 << 11) | ki);
    }
}

// ---------------- fused score+softmax+aggregate, gather form (bf16) ---------
__global__ __launch_bounds__(256) void edge_gather(
    const unsigned short* __restrict__ q, const unsigned short* __restrict__ k_,
    const unsigned short* __restrict__ v_,
    const unsigned short* __restrict__ rel_q, const unsigned short* __restrict__ rel_k,
    const unsigned short* __restrict__ rel_v,
    const int* __restrict__ row_start, const int* __restrict__ deg,
    const unsigned short* __restrict__ csr, unsigned short* __restrict__ attn)
{
    int g    = blockIdx.x * 4 + (threadIdx.x >> 6);   // 0..65535
    int lane = threadIdx.x & 63;
    int bh   = g >> 11;
    int dst  = g & (S_ - 1);
    int h    = bh & 7;
    size_t node_base = ((size_t)bh << 11);

    float qv = bf2f(q[((node_base + dst) << 6) + lane]);
    int rs = row_start[g];
    int n  = deg[g];
    const unsigned short* cs = csr + ((size_t)bh * EPB);

    float den = 0.f;
    float o   = 0.f;
    #pragma unroll 4
    for (int j = 0; j < n; ++j) {
        unsigned d = cs[rs + j];
        int ki = d & (S_ - 1);
        int r2 = d >> 11;
        float kv = bf2f(k_[((node_base + ki) << 6) + lane]);
        float rk = bf2f(rel_k[(((h << 4) + r2) << 6) + lane]);
        float rq = bf2f(rel_q[(((h << 4) + r2) << 6) + lane]);
        float p = qv * kv + qv * rk + rq * kv;
        #pragma unroll
        for (int off = 32; off >= 1; off >>= 1)
            p += __shfl_xor(p, off);
        float sf = __expf(p * (1.0f / 24.0f));   // 3*sqrt(64)=24
        float vv = bf2f(v_[((node_base + ki) << 6) + lane]);
        float rv = bf2f(rel_v[(((h << 4) + r2) << 6) + lane]);
        den += sf;
        o = fmaf(sf, vv + rv, o);
    }
    attn[((node_base + dst) << 6) + lane] = f2bf((den > 0.f) ? o / den : 0.f);
}

extern "C" void kernel_launch(void* const* d_in, const int* in_sizes, int n_in,
                              void* d_out, int out_size, void* d_ws, size_t ws_size,
                              hipStream_t stream) {
    const float* query = (const float*)d_in[0];
    const float* key   = (const float*)d_in[1];
    const float* value = (const float*)d_in[2];
    const int* start_nodes = (const int*)d_in[3];
    const int* end_nodes   = (const int*)d_in[4];
    const float* rel_q = (const float*)d_in[5];
    const float* rel_k = (const float*)d_in[6];
    const float* rel_v = (const float*)d_in[7];
    const float* Wq = (const float*)d_in[8];
    const float* bq = (const float*)d_in[9];
    const float* Wk = (const float*)d_in[10];
    const float* bk = (const float*)d_in[11];
    const float* Wv = (const float*)d_in[12];
    const float* bv = (const float*)d_in[13];
    const float* Wo = (const float*)d_in[14];
    const float* bo = (const float*)d_in[15];
    float* out = (float*)d_out;

    // Workspace (all bf16 unless noted), element counts:
    const size_t NQ = (size_t)B_ * H_ * S_ * DK_;   // 4,194,304
    const size_t NW = (size_t)D_ * D_;              // 262,144
    const size_t NR = (size_t)H_ * 2 * R_ * DK_;    // 8,192
    unsigned short* p = (unsigned short*)d_ws;
    unsigned short* qc = p;            p += NQ;   // converted inputs
    unsigned short* kc = p;            p += NQ;
    unsigned short* vc = p;            p += NQ;
    unsigned short* q  = p;            p += NQ;   // projections [B,H,S,dk]
    unsigned short* k  = p;            p += NQ;
    unsigned short* v  = p;            p += NQ;
    unsigned short* attn = p;          p += NQ;
    unsigned short* wqb = p;           p += NW;
    unsigned short* wkb = p;           p += NW;
    unsigned short* wvb = p;           p += NW;
    unsigned short* wob = p;           p += NW;
    unsigned short* rqb = p;           p += NR;
    unsigned short* rkb = p;           p += NR;
    unsigned short* rvb = p;           p += NR;
    unsigned short* csr = p;           p += (size_t)B_ * H_ * EPB;  // 1,048,576
    int* row_start = (int*)p;
    int* deg       = row_start + (size_t)B_ * H_ * S_;

    // 1) converts
    cvt_big<<<dim3(NQ / 4 / 256, 3), 256, 0, stream>>>(query, key, value, qc, kc, vc);
    cvt_small<<<dim3(NW / 4 / 256, 7), 256, 0, stream>>>(
        Wq, Wk, Wv, Wo, rel_q, rel_k, rel_v, wqb, wkb, wvb, wob, rqb, rkb, rvb);

    // 2) CSR inversion (independent of converts, but same stream is fine)
    build_csr<<<B_ * H_, 1024, 0, stream>>>(start_nodes, end_nodes, row_start, deg, csr);

    // 3) fused QKV projection
    dim3 ggrid(B_ * S_ / 128, D_ / 128, 3);   // 64 x 4 x 3
    gemm_bf16<<<ggrid, 256, 0, stream>>>(qc, kc, vc, wqb, wkb, wvb, bq, bk, bv,
                                         q, k, v, nullptr, 0);

    // 4) fused attention (gather form)
    edge_gather<<<(B_ * H_ * S_) / 4, 256, 0, stream>>>(
        q, k, v, rqb, rkb, rvb, row_start, deg, csr, attn);

    // 5) output projection (fp32 out)
    dim3 ogrid(B_ * S_ / 128, D_ / 128, 1);
    gemm_bf16<<<ogrid, 256, 0, stream>>>(attn, attn, attn, wob, wob, wob, bo, bo, bo,
                                         nullptr, nullptr, nullptr, out, 1);
}

// Round 5
// 277.351 us; speedup vs baseline: 3.3378x; 1.2421x over previous
//
#include <hip/hip_runtime.h>
#include <math.h>

// Problem constants (fixed by reference): B=4, S=2048, D=512, H=8, R=8, dk=64
#define B_ 4
#define S_ 2048
#define D_ 512
#define H_ 8
#define R_ 8
#define DK_ 64
#define NEDGE (B_*H_*2*R_*S_)   // 1,048,576
#define ELLCAP 64               // max in-degree slots; Poisson(15) tail ~2e-8

typedef __attribute__((ext_vector_type(8))) short bf16x8;
typedef __attribute__((ext_vector_type(8))) unsigned short ushort8_t;
typedef __attribute__((ext_vector_type(4))) float f32x4;

__device__ inline unsigned short f2bf(float f) {
    unsigned u = __builtin_bit_cast(unsigned, f);
    u += 0x7fffu + ((u >> 16) & 1u);   // RNE (no NaN inputs here)
    return (unsigned short)(u >> 16);
}
__device__ inline float bf2f(unsigned short u) {
    return __builtin_bit_cast(float, ((unsigned)u) << 16);
}

// ---------------- fp32 -> bf16 converts -------------------------------------
__global__ __launch_bounds__(256) void cvt_big(
    const float* __restrict__ x0, const float* __restrict__ x1, const float* __restrict__ x2,
    unsigned short* __restrict__ y0, unsigned short* __restrict__ y1, unsigned short* __restrict__ y2)
{
    int z = blockIdx.y;
    const float* x = (z == 0) ? x0 : (z == 1) ? x1 : x2;
    unsigned short* y = (z == 0) ? y0 : (z == 1) ? y1 : y2;
    size_t i = ((size_t)blockIdx.x * 256 + threadIdx.x) * 4;
    float4 v = *(const float4*)&x[i];
    *(ushort4*)&y[i] = make_ushort4(f2bf(v.x), f2bf(v.y), f2bf(v.z), f2bf(v.w));
}

__global__ __launch_bounds__(256) void cvt_small(
    const float* __restrict__ x0, const float* __restrict__ x1,
    const float* __restrict__ x2, const float* __restrict__ x3,
    const float* __restrict__ x4, const float* __restrict__ x5, const float* __restrict__ x6,
    unsigned short* __restrict__ y0, unsigned short* __restrict__ y1,
    unsigned short* __restrict__ y2, unsigned short* __restrict__ y3,
    unsigned short* __restrict__ y4, unsigned short* __restrict__ y5, unsigned short* __restrict__ y6)
{
    int z = blockIdx.y;
    const float* xs[7] = {x0, x1, x2, x3, x4, x5, x6};
    unsigned short* ys[7] = {y0, y1, y2, y3, y4, y5, y6};
    int n = (z < 4) ? (D_ * D_) : (H_ * 2 * R_ * DK_);
    size_t i = ((size_t)blockIdx.x * 256 + threadIdx.x) * 4;
    if (i >= (size_t)n) return;
    float4 v = *(const float4*)&xs[z][i];
    *(ushort4*)&ys[z][i] = make_ushort4(f2bf(v.x), f2bf(v.y), f2bf(v.z), f2bf(v.w));
}

// ---------------- bf16 GEMM: C[m,n] = sum_k A[m,k]*W[n,k] + bias[n] ---------
#define LSTR 72   // 64 + 8 shorts pad

__global__ __launch_bounds__(256) void gemm_bf16(
    const unsigned short* __restrict__ A0, const unsigned short* __restrict__ A1,
    const unsigned short* __restrict__ A2,
    const unsigned short* __restrict__ W0, const unsigned short* __restrict__ W1,
    const unsigned short* __restrict__ W2,
    const float* __restrict__ bi0, const float* __restrict__ bi1, const float* __restrict__ bi2,
    unsigned short* __restrict__ C0, unsigned short* __restrict__ C1,
    unsigned short* __restrict__ C2,
    float* __restrict__ Cf, int a_bhsd)
{
    __shared__ unsigned short As[128 * LSTR];
    __shared__ unsigned short Bs[128 * LSTR];
    const int z = blockIdx.z;
    const unsigned short* A = (z == 0) ? A0 : (z == 1) ? A1 : A2;
    const unsigned short* W = (z == 0) ? W0 : (z == 1) ? W1 : W2;
    const float* bias        = (z == 0) ? bi0 : (z == 1) ? bi1 : bi2;
    unsigned short* C        = (z == 0) ? C0 : (z == 1) ? C1 : C2;

    const int t    = threadIdx.x;
    const int lane = t & 63;
    const int wid  = t >> 6;
    const int wm   = wid >> 1, wn = wid & 1;
    const int m0   = blockIdx.x * 128;
    const int n0   = blockIdx.y * 128;

    f32x4 acc[4][4] = {};

    for (int kk = 0; kk < D_; kk += 64) {
        #pragma unroll
        for (int i = 0; i < 4; ++i) {
            int fidx = t + i * 256;
            int row  = fidx >> 3;
            int c    = fidx & 7;
            const unsigned short* ap;
            if (a_bhsd) {
                int m = m0 + row;
                int b = m >> 11, s = m & (S_ - 1);
                int h = kk >> 6;
                ap = A + ((((size_t)b * H_ + h) * S_ + s) << 6) + c * 8;
            } else {
                ap = A + (size_t)(m0 + row) * D_ + kk + c * 8;
            }
            *(ushort8_t*)&As[row * LSTR + c * 8] = *(const ushort8_t*)ap;
            *(ushort8_t*)&Bs[row * LSTR + c * 8] =
                *(const ushort8_t*)(W + (size_t)(n0 + row) * D_ + kk + c * 8);
        }
        __syncthreads();

        #pragma unroll
        for (int ks = 0; ks < 64; ks += 32) {
            bf16x8 af[4], bfr[4];
            #pragma unroll
            for (int mi = 0; mi < 4; ++mi)
                af[mi] = *(const bf16x8*)&As[(wm * 64 + mi * 16 + (lane & 15)) * LSTR + ks + (lane >> 4) * 8];
            #pragma unroll
            for (int nj = 0; nj < 4; ++nj)
                bfr[nj] = *(const bf16x8*)&Bs[(wn * 64 + nj * 16 + (lane & 15)) * LSTR + ks + (lane >> 4) * 8];
            #pragma unroll
            for (int mi = 0; mi < 4; ++mi)
                #pragma unroll
                for (int nj = 0; nj < 4; ++nj)
                    acc[mi][nj] = __builtin_amdgcn_mfma_f32_16x16x32_bf16(af[mi], bfr[nj], acc[mi][nj], 0, 0, 0);
        }
        __syncthreads();
    }

    #pragma unroll
    for (int mi = 0; mi < 4; ++mi) {
        #pragma unroll
        for (int nj = 0; nj < 4; ++nj) {
            #pragma unroll
            for (int r = 0; r < 4; ++r) {
                int m = m0 + wm * 64 + mi * 16 + (lane >> 4) * 4 + r;
                int n = n0 + wn * 64 + nj * 16 + (lane & 15);
                float val = acc[mi][nj][r] + bias[n];
                if (Cf) {
                    Cf[(size_t)m * D_ + n] = val;
                } else {
                    int b = m >> 11, s = m & (S_ - 1);
                    int h = n >> 6,  d = n & 63;
                    C[((((size_t)b * H_ + h) * S_ + s) << 6) + d] = f2bf(val);
                }
            }
        }
    }
}

// ---------------- ELL build: thread per edge, global atomics ----------------
// Edge (bh,r2,s): masked iff r2==0 || start==-1. dst = r2<R ? end : start,
// src(ki) = r2<R ? start : end. Packed: (r2<<11)|ki (15 bits).
__global__ __launch_bounds__(256) void fill_ell(
    const int* __restrict__ start_nodes, const int* __restrict__ end_nodes,
    int* __restrict__ deg, unsigned short* __restrict__ ell)
{
    int f = blockIdx.x * 256 + threadIdx.x;   // (bh, r2, s) flat
    int s    = f & (S_ - 1);
    int rest = f >> 11;
    int r2   = rest & 15;
    int bh   = rest >> 4;
    if (r2 == 0) return;
    int r  = r2 & 7;
    int idx = (bh * R_ + r) * S_ + s;
    int sn = start_nodes[idx];
    if (sn == -1) return;
    int en = end_nodes[idx];
    int dst = (r2 < R_) ? en : sn;
    int ki  = (r2 < R_) ? sn : en;
    int g = bh * S_ + dst;
    int pos = atomicAdd(&deg[g], 1);
    if (pos < ELLCAP)
        ell[(size_t)g * ELLCAP + pos] = (unsigned short)((r2 << 11) | ki);
}

// ---------------- fused score+softmax+aggregate -----------------------------
// One wave per dst node; 4 edges/iteration, 16 lanes/edge, 4 dk elems/lane.
// XCD swizzle: 4 consecutive bh per XCD (k+v working set 4 MB -> L2-resident).
__global__ __launch_bounds__(256) void edge_gather(
    const unsigned short* __restrict__ q, const unsigned short* __restrict__ k_,
    const unsigned short* __restrict__ v_,
    const unsigned short* __restrict__ rel_q, const unsigned short* __restrict__ rel_k,
    const unsigned short* __restrict__ rel_v,
    const int* __restrict__ deg, const unsigned short* __restrict__ ell,
    unsigned short* __restrict__ attn)
{
    int raw = blockIdx.x;
    int xcd = raw & 7;
    int loc = raw >> 3;                 // 0..2047
    int bh  = xcd * 4 + (loc >> 9);     // 4 bh per XCD
    int wid = threadIdx.x >> 6;
    int dst = (loc & 511) * 4 + wid;
    int lane = threadIdx.x & 63;
    int grp = lane >> 4;                // edge slot within group-of-4
    int sub = lane & 15;                // dk chunk (4 elems)
    int h = bh & 7;
    int g = bh * S_ + dst;
    size_t node_base = ((size_t)bh << 11);

    ushort4 q4 = *(const ushort4*)&q[((node_base + dst) << 6) + sub * 4];
    float qv0 = bf2f(q4.x), qv1 = bf2f(q4.y), qv2 = bf2f(q4.z), qv3 = bf2f(q4.w);

    int n = deg[g];
    if (n > ELLCAP) n = ELLCAP;
    const unsigned short* row = ell + (size_t)g * ELLCAP;

    float den = 0.f;
    float o0 = 0.f, o1 = 0.f, o2 = 0.f, o3 = 0.f;
    for (int j = 0; j < n; j += 4) {
        int slot = j + grp;                 // < ELLCAP always (CAP % 4 == 0)
        unsigned d = row[slot];             // tail slots: poison -> masked below
        int ki = d & (S_ - 1);
        int r2 = (d >> 11) & 15;
        bool valid = slot < n;
        ushort4 k4  = *(const ushort4*)&k_  [((node_base + ki) << 6) + sub * 4];
        ushort4 rk4 = *(const ushort4*)&rel_k[(((h << 4) + r2) << 6) + sub * 4];
        ushort4 rq4 = *(const ushort4*)&rel_q[(((h << 4) + r2) << 6) + sub * 4];
        float p;
        p  = bf2f(k4.x) * (qv0 + bf2f(rq4.x)) + qv0 * bf2f(rk4.x);
        p += bf2f(k4.y) * (qv1 + bf2f(rq4.y)) + qv1 * bf2f(rk4.y);
        p += bf2f(k4.z) * (qv2 + bf2f(rq4.z)) + qv2 * bf2f(rk4.z);
        p += bf2f(k4.w) * (qv3 + bf2f(rq4.w)) + qv3 * bf2f(rk4.w);
        // reduce across the 16 lanes of this edge's group (xor of bits 0..3)
        p += __shfl_xor(p, 1);
        p += __shfl_xor(p, 2);
        p += __shfl_xor(p, 4);
        p += __shfl_xor(p, 8);
        float sf = valid ? __expf(p * (1.0f / 24.0f)) : 0.f;   // 3*sqrt(64)=24
        ushort4 v4  = *(const ushort4*)&v_  [((node_base + ki) << 6) + sub * 4];
        ushort4 rv4 = *(const ushort4*)&rel_v[(((h << 4) + r2) << 6) + sub * 4];
        den += sf;
        o0 = fmaf(sf, bf2f(v4.x) + bf2f(rv4.x), o0);
        o1 = fmaf(sf, bf2f(v4.y) + bf2f(rv4.y), o1);
        o2 = fmaf(sf, bf2f(v4.z) + bf2f(rv4.z), o2);
        o3 = fmaf(sf, bf2f(v4.w) + bf2f(rv4.w), o3);
    }
    // cross-group reduction (one-time epilogue)
    den += __shfl_xor(den, 16); den += __shfl_xor(den, 32);
    o0  += __shfl_xor(o0, 16);  o0  += __shfl_xor(o0, 32);
    o1  += __shfl_xor(o1, 16);  o1  += __shfl_xor(o1, 32);
    o2  += __shfl_xor(o2, 16);  o2  += __shfl_xor(o2, 32);
    o3  += __shfl_xor(o3, 16);  o3  += __shfl_xor(o3, 32);
    if (grp == 0) {
        float inv = (den > 0.f) ? 1.0f / den : 0.f;
        ushort4 r = make_ushort4(f2bf(o0 * inv), f2bf(o1 * inv),
                                 f2bf(o2 * inv), f2bf(o3 * inv));
        *(ushort4*)&attn[((node_base + dst) << 6) + sub * 4] = r;
    }
}

extern "C" void kernel_launch(void* const* d_in, const int* in_sizes, int n_in,
                              void* d_out, int out_size, void* d_ws, size_t ws_size,
                              hipStream_t stream) {
    const float* query = (const float*)d_in[0];
    const float* key   = (const float*)d_in[1];
    const float* value = (const float*)d_in[2];
    const int* start_nodes = (const int*)d_in[3];
    const int* end_nodes   = (const int*)d_in[4];
    const float* rel_q = (const float*)d_in[5];
    const float* rel_k = (const float*)d_in[6];
    const float* rel_v = (const float*)d_in[7];
    const float* Wq = (const float*)d_in[8];
    const float* bq = (const float*)d_in[9];
    const float* Wk = (const float*)d_in[10];
    const float* bk = (const float*)d_in[11];
    const float* Wv = (const float*)d_in[12];
    const float* bv = (const float*)d_in[13];
    const float* Wo = (const float*)d_in[14];
    const float* bo = (const float*)d_in[15];
    float* out = (float*)d_out;

    const size_t NQ = (size_t)B_ * H_ * S_ * DK_;   // 4,194,304
    const size_t NW = (size_t)D_ * D_;              // 262,144
    const size_t NR = (size_t)H_ * 2 * R_ * DK_;    // 8,192
    const size_t NG = (size_t)B_ * H_ * S_;         // 65,536 nodes
    unsigned short* p = (unsigned short*)d_ws;
    unsigned short* qc = p;            p += NQ;
    unsigned short* kc = p;            p += NQ;
    unsigned short* vc = p;            p += NQ;
    unsigned short* q  = p;            p += NQ;
    unsigned short* k  = p;            p += NQ;
    unsigned short* v  = p;            p += NQ;
    unsigned short* attn = p;          p += NQ;
    unsigned short* wqb = p;           p += NW;
    unsigned short* wkb = p;           p += NW;
    unsigned short* wvb = p;           p += NW;
    unsigned short* wob = p;           p += NW;
    unsigned short* rqb = p;           p += NR;
    unsigned short* rkb = p;           p += NR;
    unsigned short* rvb = p;           p += NR;
    unsigned short* ell = p;           p += NG * ELLCAP;   // 8 MB
    int* deg = (int*)p;

    // 1) converts
    cvt_big<<<dim3(NQ / 4 / 256, 3), 256, 0, stream>>>(query, key, value, qc, kc, vc);
    cvt_small<<<dim3(NW / 4 / 256, 7), 256, 0, stream>>>(
        Wq, Wk, Wv, Wo, rel_q, rel_k, rel_v, wqb, wkb, wvb, wob, rqb, rkb, rvb);

    // 2) ELL inversion (deg zero-init + atomic placement)
    hipMemsetAsync(deg, 0, NG * sizeof(int), stream);
    fill_ell<<<NEDGE / 256, 256, 0, stream>>>(start_nodes, end_nodes, deg, ell);

    // 3) fused QKV projection
    dim3 ggrid(B_ * S_ / 128, D_ / 128, 3);
    gemm_bf16<<<ggrid, 256, 0, stream>>>(qc, kc, vc, wqb, wkb, wvb, bq, bk, bv,
                                         q, k, v, nullptr, 0);

    // 4) fused attention (gather form, ELL)
    edge_gather<<<(B_ * H_ * S_) / 4, 256, 0, stream>>>(
        q, k, v, rqb, rkb, rvb, deg, ell, attn);

    // 5) output projection (fp32 out)
    dim3 ogrid(B_ * S_ / 128, D_ / 128, 1);
    gemm_bf16<<<ogrid, 256, 0, stream>>>(attn, attn, attn, wob, wob, wob, bo, bo, bo,
                                         nullptr, nullptr, nullptr, out, 1);
}

// Round 6
// 244.189 us; speedup vs baseline: 3.7911x; 1.1358x over previous
//
#include <hip/hip_runtime.h>
#include <math.h>

// Problem constants (fixed by reference): B=4, S=2048, D=512, H=8, R=8, dk=64
#define B_ 4
#define S_ 2048
#define D_ 512
#define H_ 8
#define R_ 8
#define DK_ 64
#define NEDGE (B_*H_*2*R_*S_)   // 1,048,576
#define ELLCAP 64               // max in-degree slots; Poisson(15) tail ~2e-8

typedef __attribute__((ext_vector_type(8))) short bf16x8;
typedef __attribute__((ext_vector_type(8))) unsigned short ushort8_t;
typedef __attribute__((ext_vector_type(4))) float f32x4;

#define AS1q const __attribute__((address_space(1)))
#define AS3q __attribute__((address_space(3)))

__device__ inline unsigned short f2bf(float f) {
    unsigned u = __builtin_bit_cast(unsigned, f);
    u += 0x7fffu + ((u >> 16) & 1u);   // RNE (no NaN inputs here)
    return (unsigned short)(u >> 16);
}
__device__ inline float bf2f(unsigned short u) {
    return __builtin_bit_cast(float, ((unsigned)u) << 16);
}

// ---------------- fp32 -> bf16 converts -------------------------------------
__global__ __launch_bounds__(256) void cvt_big(
    const float* __restrict__ x0, const float* __restrict__ x1, const float* __restrict__ x2,
    unsigned short* __restrict__ y0, unsigned short* __restrict__ y1, unsigned short* __restrict__ y2)
{
    int z = blockIdx.y;
    const float* x = (z == 0) ? x0 : (z == 1) ? x1 : x2;
    unsigned short* y = (z == 0) ? y0 : (z == 1) ? y1 : y2;
    size_t i = ((size_t)blockIdx.x * 256 + threadIdx.x) * 4;
    float4 v = *(const float4*)&x[i];
    *(ushort4*)&y[i] = make_ushort4(f2bf(v.x), f2bf(v.y), f2bf(v.z), f2bf(v.w));
}

__global__ __launch_bounds__(256) void cvt_small(
    const float* __restrict__ x0, const float* __restrict__ x1,
    const float* __restrict__ x2, const float* __restrict__ x3,
    const float* __restrict__ x4, const float* __restrict__ x5, const float* __restrict__ x6,
    unsigned short* __restrict__ y0, unsigned short* __restrict__ y1,
    unsigned short* __restrict__ y2, unsigned short* __restrict__ y3,
    unsigned short* __restrict__ y4, unsigned short* __restrict__ y5, unsigned short* __restrict__ y6)
{
    int z = blockIdx.y;
    const float* xs[7] = {x0, x1, x2, x3, x4, x5, x6};
    unsigned short* ys[7] = {y0, y1, y2, y3, y4, y5, y6};
    int n = (z < 4) ? (D_ * D_) : (H_ * 2 * R_ * DK_);
    size_t i = ((size_t)blockIdx.x * 256 + threadIdx.x) * 4;
    if (i >= (size_t)n) return;
    float4 v = *(const float4*)&xs[z][i];
    *(ushort4*)&ys[z][i] = make_ushort4(f2bf(v.x), f2bf(v.y), f2bf(v.z), f2bf(v.w));
}

// ---------------- bf16 GEMM, m97-style: global_load_lds + XOR-swizzled LDS --
// C[m,n] = sum_k A[m,k]*W[n,k] + bias[n]. 128x128 tile, BK=64, 4 waves 2x2,
// each wave 64x64 via 4x4 MFMA 16x16x32. LDS rows are unpadded 64 shorts
// (128 B); chunk swizzle c_phys = c_log ^ (row&7) keeps ds_read_b128 at
// 2 lanes/bank (free) while satisfying global_load_lds's lane-linear dest.
__global__ __launch_bounds__(256) void gemm_bf16(
    const unsigned short* __restrict__ A0, const unsigned short* __restrict__ A1,
    const unsigned short* __restrict__ A2,
    const unsigned short* __restrict__ W0, const unsigned short* __restrict__ W1,
    const unsigned short* __restrict__ W2,
    const float* __restrict__ bi0, const float* __restrict__ bi1, const float* __restrict__ bi2,
    unsigned short* __restrict__ C0, unsigned short* __restrict__ C1,
    unsigned short* __restrict__ C2,
    float* __restrict__ Cf, int a_bhsd)
{
    __shared__ unsigned short As[128 * 64];
    __shared__ unsigned short Bs[128 * 64];
    const int z = blockIdx.z;
    const unsigned short* A = (z == 0) ? A0 : (z == 1) ? A1 : A2;
    const unsigned short* W = (z == 0) ? W0 : (z == 1) ? W1 : W2;
    const float* bias        = (z == 0) ? bi0 : (z == 1) ? bi1 : bi2;
    unsigned short* C        = (z == 0) ? C0 : (z == 1) ? C1 : C2;

    const int t    = threadIdx.x;
    const int lane = t & 63;
    const int w    = t >> 6;
    const int wm   = w >> 1, wn = w & 1;
    const int m0   = blockIdx.x * 128;
    const int n0   = blockIdx.y * 128;

    const int lr    = lane >> 3;           // row within 8-row stage chunk
    const int cglob = (lane & 7) ^ lr;     // swizzled global source chunk

    f32x4 acc[4][4] = {};

    for (int kk = 0; kk < D_; kk += 64) {
        #pragma unroll
        for (int i = 0; i < 4; ++i) {
            int rowl = w * 32 + i * 8;         // wave-uniform LDS row base
            int m = m0 + rowl + lr;
            const unsigned short* ga;
            if (a_bhsd) {
                int b = m >> 11, s = m & (S_ - 1), h = kk >> 6;
                ga = A + ((((size_t)b * H_ + h) * S_ + s) << 6) + cglob * 8;
            } else {
                ga = A + (size_t)m * D_ + kk + cglob * 8;
            }
            __builtin_amdgcn_global_load_lds((AS1q unsigned*)ga,
                (AS3q unsigned*)(As + rowl * 64), 16, 0, 0);
            const unsigned short* gb =
                W + (size_t)(n0 + rowl + lr) * D_ + kk + cglob * 8;
            __builtin_amdgcn_global_load_lds((AS1q unsigned*)gb,
                (AS3q unsigned*)(Bs + rowl * 64), 16, 0, 0);
        }
        __syncthreads();

        #pragma unroll
        for (int ks = 0; ks < 64; ks += 32) {
            const int c0 = ks >> 3;            // 0 or 4
            bf16x8 af[4], bfr[4];
            #pragma unroll
            for (int mi = 0; mi < 4; ++mi) {
                int row = wm * 64 + mi * 16 + (lane & 15);
                int cp  = (c0 + (lane >> 4)) ^ (lane & 7);
                af[mi] = *(const bf16x8*)&As[row * 64 + cp * 8];
            }
            #pragma unroll
            for (int nj = 0; nj < 4; ++nj) {
                int row = wn * 64 + nj * 16 + (lane & 15);
                int cp  = (c0 + (lane >> 4)) ^ (lane & 7);
                bfr[nj] = *(const bf16x8*)&Bs[row * 64 + cp * 8];
            }
            #pragma unroll
            for (int mi = 0; mi < 4; ++mi)
                #pragma unroll
                for (int nj = 0; nj < 4; ++nj)
                    acc[mi][nj] = __builtin_amdgcn_mfma_f32_16x16x32_bf16(af[mi], bfr[nj], acc[mi][nj], 0, 0, 0);
        }
        __syncthreads();
    }

    // epilogue: C/D layout col = lane&15, row = (lane>>4)*4 + reg
    #pragma unroll
    for (int mi = 0; mi < 4; ++mi) {
        #pragma unroll
        for (int nj = 0; nj < 4; ++nj) {
            #pragma unroll
            for (int r = 0; r < 4; ++r) {
                int m = m0 + wm * 64 + mi * 16 + (lane >> 4) * 4 + r;
                int n = n0 + wn * 64 + nj * 16 + (lane & 15);
                float val = acc[mi][nj][r] + bias[n];
                if (Cf) {
                    Cf[(size_t)m * D_ + n] = val;
                } else {
                    int b = m >> 11, s = m & (S_ - 1);
                    int h = n >> 6,  d = n & 63;
                    C[((((size_t)b * H_ + h) * S_ + s) << 6) + d] = f2bf(val);
                }
            }
        }
    }
}

// ---------------- ELL build: thread per edge, global atomics ----------------
__global__ __launch_bounds__(256) void fill_ell(
    const int* __restrict__ start_nodes, const int* __restrict__ end_nodes,
    int* __restrict__ deg, unsigned short* __restrict__ ell)
{
    int f = blockIdx.x * 256 + threadIdx.x;   // (bh, r2, s) flat
    int s    = f & (S_ - 1);
    int rest = f >> 11;
    int r2   = rest & 15;
    int bh   = rest >> 4;
    if (r2 == 0) return;
    int r  = r2 & 7;
    int idx = (bh * R_ + r) * S_ + s;
    int sn = start_nodes[idx];
    if (sn == -1) return;
    int en = end_nodes[idx];
    int dst = (r2 < R_) ? en : sn;
    int ki  = (r2 < R_) ? sn : en;
    int g = bh * S_ + dst;
    int pos = atomicAdd(&deg[g], 1);
    if (pos < ELLCAP)
        ell[(size_t)g * ELLCAP + pos] = (unsigned short)((r2 << 11) | ki);
}

// ---------------- fused score+softmax+aggregate -----------------------------
// One wave per dst node; 8 edges/iteration, 8 lanes/edge, 8 dk elems/lane
// (ushort8 = 16 B loads). ELL row prefetched once (row[lane]) and edges
// distributed via __shfl -> removes one L2-latency level per iteration.
__global__ __launch_bounds__(256) void edge_gather(
    const unsigned short* __restrict__ q, const unsigned short* __restrict__ k_,
    const unsigned short* __restrict__ v_,
    const unsigned short* __restrict__ rel_q, const unsigned short* __restrict__ rel_k,
    const unsigned short* __restrict__ rel_v,
    const int* __restrict__ deg, const unsigned short* __restrict__ ell,
    unsigned short* __restrict__ attn)
{
    int raw = blockIdx.x;
    int xcd = raw & 7;
    int loc = raw >> 3;                 // 0..2047
    int bh  = xcd * 4 + (loc >> 9);     // 4 bh per XCD (k+v slice L2-resident)
    int wid = threadIdx.x >> 6;
    int dst = (loc & 511) * 4 + wid;
    int lane = threadIdx.x & 63;
    int grp = lane >> 3;                // edge slot within group-of-8
    int sub = lane & 7;                 // dk chunk (8 elems)
    int h = bh & 7;
    int g = bh * S_ + dst;
    size_t node_base = ((size_t)bh << 11);

    ushort8_t q8 = *(const ushort8_t*)&q[((node_base + dst) << 6) + sub * 8];
    float qv[8];
    #pragma unroll
    for (int i = 0; i < 8; ++i) qv[i] = bf2f(q8[i]);

    int n = deg[g];
    if (n > ELLCAP) n = ELLCAP;
    int d_all = (int)ell[(size_t)g * ELLCAP + lane];   // full row, 128 B coalesced

    float den = 0.f;
    float o[8] = {};
    #pragma unroll 2
    for (int j = 0; j < n; j += 8) {
        int slot = j + grp;
        int d = __shfl(d_all, slot);
        bool valid = slot < n;
        int ki = d & (S_ - 1);
        int r2 = (d >> 11) & 15;
        ushort8_t k8  = *(const ushort8_t*)&k_  [((node_base + ki) << 6) + sub * 8];
        ushort8_t rk8 = *(const ushort8_t*)&rel_k[(((h << 4) + r2) << 6) + sub * 8];
        ushort8_t rq8 = *(const ushort8_t*)&rel_q[(((h << 4) + r2) << 6) + sub * 8];
        float p = 0.f;
        #pragma unroll
        for (int i = 0; i < 8; ++i)
            p = fmaf(bf2f(k8[i]), qv[i] + bf2f(rq8[i]),
                     fmaf(qv[i], bf2f(rk8[i]), p));
        p += __shfl_xor(p, 1);
        p += __shfl_xor(p, 2);
        p += __shfl_xor(p, 4);
        float sf = valid ? __expf(p * (1.0f / 24.0f)) : 0.f;   // 3*sqrt(64)=24
        ushort8_t v8  = *(const ushort8_t*)&v_  [((node_base + ki) << 6) + sub * 8];
        ushort8_t rv8 = *(const ushort8_t*)&rel_v[(((h << 4) + r2) << 6) + sub * 8];
        den += sf;
        #pragma unroll
        for (int i = 0; i < 8; ++i)
            o[i] = fmaf(sf, bf2f(v8[i]) + bf2f(rv8[i]), o[i]);
    }
    // cross-group reduction (xor 8,16,32 preserves sub)
    den += __shfl_xor(den, 8); den += __shfl_xor(den, 16); den += __shfl_xor(den, 32);
    #pragma unroll
    for (int i = 0; i < 8; ++i) {
        o[i] += __shfl_xor(o[i], 8);
        o[i] += __shfl_xor(o[i], 16);
        o[i] += __shfl_xor(o[i], 32);
    }
    if (grp == 0) {
        float inv = (den > 0.f) ? 1.0f / den : 0.f;
        ushort8_t r;
        #pragma unroll
        for (int i = 0; i < 8; ++i) r[i] = f2bf(o[i] * inv);
        *(ushort8_t*)&attn[((node_base + dst) << 6) + sub * 8] = r;
    }
}

extern "C" void kernel_launch(void* const* d_in, const int* in_sizes, int n_in,
                              void* d_out, int out_size, void* d_ws, size_t ws_size,
                              hipStream_t stream) {
    const float* query = (const float*)d_in[0];
    const float* key   = (const float*)d_in[1];
    const float* value = (const float*)d_in[2];
    const int* start_nodes = (const int*)d_in[3];
    const int* end_nodes   = (const int*)d_in[4];
    const float* rel_q = (const float*)d_in[5];
    const float* rel_k = (const float*)d_in[6];
    const float* rel_v = (const float*)d_in[7];
    const float* Wq = (const float*)d_in[8];
    const float* bq = (const float*)d_in[9];
    const float* Wk = (const float*)d_in[10];
    const float* bk = (const float*)d_in[11];
    const float* Wv = (const float*)d_in[12];
    const float* bv = (const float*)d_in[13];
    const float* Wo = (const float*)d_in[14];
    const float* bo = (const float*)d_in[15];
    float* out = (float*)d_out;

    const size_t NQ = (size_t)B_ * H_ * S_ * DK_;   // 4,194,304
    const size_t NW = (size_t)D_ * D_;              // 262,144
    const size_t NR = (size_t)H_ * 2 * R_ * DK_;    // 8,192
    const size_t NG = (size_t)B_ * H_ * S_;         // 65,536 nodes
    unsigned short* p = (unsigned short*)d_ws;
    unsigned short* qc = p;            p += NQ;
    unsigned short* kc = p;            p += NQ;
    unsigned short* vc = p;            p += NQ;
    unsigned short* q  = p;            p += NQ;
    unsigned short* k  = p;            p += NQ;
    unsigned short* v  = p;            p += NQ;
    unsigned short* attn = p;          p += NQ;
    unsigned short* wqb = p;           p += NW;
    unsigned short* wkb = p;           p += NW;
    unsigned short* wvb = p;           p += NW;
    unsigned short* wob = p;           p += NW;
    unsigned short* rqb = p;           p += NR;
    unsigned short* rkb = p;           p += NR;
    unsigned short* rvb = p;           p += NR;
    unsigned short* ell = p;           p += NG * ELLCAP;   // 8 MB
    int* deg = (int*)p;

    // 1) converts
    cvt_big<<<dim3(NQ / 4 / 256, 3), 256, 0, stream>>>(query, key, value, qc, kc, vc);
    cvt_small<<<dim3(NW / 4 / 256, 7), 256, 0, stream>>>(
        Wq, Wk, Wv, Wo, rel_q, rel_k, rel_v, wqb, wkb, wvb, wob, rqb, rkb, rvb);

    // 2) ELL inversion (deg zero-init + atomic placement)
    hipMemsetAsync(deg, 0, NG * sizeof(int), stream);
    fill_ell<<<NEDGE / 256, 256, 0, stream>>>(start_nodes, end_nodes, deg, ell);

    // 3) fused QKV projection
    dim3 ggrid(B_ * S_ / 128, D_ / 128, 3);
    gemm_bf16<<<ggrid, 256, 0, stream>>>(qc, kc, vc, wqb, wkb, wvb, bq, bk, bv,
                                         q, k, v, nullptr, 0);

    // 4) fused attention (gather form, ELL)
    edge_gather<<<(B_ * H_ * S_) / 4, 256, 0, stream>>>(
        q, k, v, rqb, rkb, rvb, deg, ell, attn);

    // 5) output projection (fp32 out)
    dim3 ogrid(B_ * S_ / 128, D_ / 128, 1);
    gemm_bf16<<<ogrid, 256, 0, stream>>>(attn, attn, attn, wob, wob, wob, bo, bo, bo,
                                         nullptr, nullptr, nullptr, out, 1);
}